// Round 6
// baseline (84.409 us; speedup 1.0000x reference)
//
#include <hip/hip_runtime.h>
#include <float.h>

#define BB 16
#define MM 32
#define KK 20
#define AA 8
#define TT 30
#define TD 60          // T*D floats per trajectory
#define KT 22          // target rows: 20 real + gt (row 20) + dummy (row 21)
#define RS 9           // LDS row stride in float4 (36 floats: 32 t-slots + banking pad)
#define NSS 8          // s-iters, 4 t-steps each (t 0..31; slots 30,31 zero)
#define PDS 21         // pd row stride in floats

// One block = 4 waves = 4 m's sharing the target tile, for a fixed (b, a).
// SoA LDS (x-rows / y-rows separate) so the inner loop runs on float4 ->
// compiler can emit v_pk_*_f32 (halves non-sqrt VALU issue).
// k-map: k = tk + 5i (tk<5); kp = tkp + 11j (tkp<11); 55 lanes cover 20x22.
// Rows at 144B stride: 4 i-addresses hit bank-quads {0,20,8,28}+4tk (disjoint),
// 11 tkp-addresses worst-case 2-way (free).
__global__ __launch_bounds__(256, 4) void imle_part_kernel(
    const float* __restrict__ gen,   // B M K A T D
    const float* __restrict__ tgt,   // B K A T D
    const float* __restrict__ gt,    // B A T D
    float* __restrict__ ws_cham,     // [B][M][A]
    float* __restrict__ ws_gt)       // [B][M][A]
{
    __shared__ float4 sgx[4][KK][RS];   // gen x-coords, x50
    __shared__ float4 sgy[4][KK][RS];   // gen y-coords, x50
    __shared__ float4 stx[KT][RS];      // target/gt/dummy x
    __shared__ float4 sty[KT][RS];      // target/gt/dummy y
    __shared__ float  pd[4][KK][PDS];   // per-m pairwise mean distances

    const int blk = blockIdx.x;        // grid = B*A*(M/4) = 1024
    const int mg = blk & 7;
    const int a  = (blk >> 3) & 7;
    const int b  = blk >> 6;
    const int m0 = mg * 4;
    const int tid = threadIdx.x;

    // ---- stage gen: 80 rows x 15 float4, transpose AoS->SoA, scale x50 ----
    for (int idx = tid; idx < 80 * 15; idx += 256) {
        int row = idx / 15, q = idx - row * 15;
        int mi = row / KK, k = row - mi * KK;
        float4 v = ((const float4*)(gen +
            (size_t)(((b * MM + m0 + mi) * KK + k) * AA + a) * TD))[q];
        ((float2*)&sgx[mi][k][0])[q] = make_float2(v.x * 50.f, v.z * 50.f);
        ((float2*)&sgy[mi][k][0])[q] = make_float2(v.y * 50.f, v.w * 50.f);
    }
    // ---- stage target rows (x50), gt row 20 (metric), dummy row 21 (zeros) ----
    for (int idx = tid; idx < KT * 15; idx += 256) {
        int row = idx / 15, q = idx - row * 15;
        float4 v;
        if (row < KK) {
            v = ((const float4*)(tgt + (size_t)((b * KK + row) * AA + a) * TD))[q];
            v.x *= 50.f; v.y *= 50.f; v.z *= 50.f; v.w *= 50.f;
        } else if (row == KK) {
            v = ((const float4*)(gt + (size_t)(b * AA + a) * TD))[q];
        } else {
            v = make_float4(0.f, 0.f, 0.f, 0.f);
        }
        ((float2*)&stx[row][0])[q] = make_float2(v.x, v.z);
        ((float2*)&sty[row][0])[q] = make_float2(v.y, v.w);
    }
    // ---- zero t-slots 30,31 of every row (pad contributes sqrt(0)=0) ----
    for (int idx = tid; idx < 102; idx += 256) {
        float2 z = make_float2(0.f, 0.f);
        if (idx < 80) {
            int mi = idx / KK, k = idx - mi * KK;
            ((float2*)&sgx[mi][k][0])[15] = z;
            ((float2*)&sgy[mi][k][0])[15] = z;
        } else {
            int row = idx - 80;
            ((float2*)&stx[row][0])[15] = z;
            ((float2*)&sty[row][0])[15] = z;
        }
    }
    __syncthreads();

    const int w = tid >> 6;        // wave id -> m offset
    const int lane = tid & 63;

    // ---- pairwise distances: 4x2 register tile, packed-f32 over 4 t-steps ----
    if (lane < 55) {
        const int tk  = lane / 11;       // k  = tk + 5i
        const int tkp = lane - tk * 11;  // kp = tkp + 11j
        float4 acc[4][2];
#pragma unroll
        for (int i = 0; i < 4; ++i) {
            acc[i][0] = make_float4(0.f, 0.f, 0.f, 0.f);
            acc[i][1] = make_float4(0.f, 0.f, 0.f, 0.f);
        }
#pragma unroll 2
        for (int s = 0; s < NSS; ++s) {
            float4 tx0 = stx[tkp][s],      ty0 = sty[tkp][s];
            float4 tx1 = stx[tkp + 11][s], ty1 = sty[tkp + 11][s];
#pragma unroll
            for (int i = 0; i < 4; ++i) {
                float4 gx = sgx[w][tk + 5 * i][s];
                float4 gy = sgy[w][tk + 5 * i][s];
                // j = 0
                {
                    float4 dx = make_float4(gx.x - tx0.x, gx.y - tx0.y, gx.z - tx0.z, gx.w - tx0.w);
                    float4 dy = make_float4(gy.x - ty0.x, gy.y - ty0.y, gy.z - ty0.z, gy.w - ty0.w);
                    float4 d2 = make_float4(fmaf(dy.x, dy.x, dx.x * dx.x),
                                            fmaf(dy.y, dy.y, dx.y * dx.y),
                                            fmaf(dy.z, dy.z, dx.z * dx.z),
                                            fmaf(dy.w, dy.w, dx.w * dx.w));
                    acc[i][0].x += __builtin_amdgcn_sqrtf(d2.x);
                    acc[i][0].y += __builtin_amdgcn_sqrtf(d2.y);
                    acc[i][0].z += __builtin_amdgcn_sqrtf(d2.z);
                    acc[i][0].w += __builtin_amdgcn_sqrtf(d2.w);
                }
                // j = 1
                {
                    float4 dx = make_float4(gx.x - tx1.x, gx.y - tx1.y, gx.z - tx1.z, gx.w - tx1.w);
                    float4 dy = make_float4(gy.x - ty1.x, gy.y - ty1.y, gy.z - ty1.z, gy.w - ty1.w);
                    float4 d2 = make_float4(fmaf(dy.x, dy.x, dx.x * dx.x),
                                            fmaf(dy.y, dy.y, dx.y * dx.y),
                                            fmaf(dy.z, dy.z, dx.z * dx.z),
                                            fmaf(dy.w, dy.w, dx.w * dx.w));
                    acc[i][1].x += __builtin_amdgcn_sqrtf(d2.x);
                    acc[i][1].y += __builtin_amdgcn_sqrtf(d2.y);
                    acc[i][1].z += __builtin_amdgcn_sqrtf(d2.z);
                    acc[i][1].w += __builtin_amdgcn_sqrtf(d2.w);
                }
            }
        }
        const float inv_t = 1.0f / TT;
#pragma unroll
        for (int i = 0; i < 4; ++i) {
            float s0 = (acc[i][0].x + acc[i][0].y) + (acc[i][0].z + acc[i][0].w);
            pd[w][tk + 5 * i][tkp] = s0 * inv_t;          // kp = tkp <= 10, always real
            float s1 = (acc[i][1].x + acc[i][1].y) + (acc[i][1].z + acc[i][1].w);
            if (tkp + 11 <= KK)                           // col 21 is dummy
                pd[w][tk + 5 * i][tkp + 11] = s1 * inv_t;
        }
    }
    __syncthreads();

    // ---- row/col mins over 20x20 + gt col, per wave / per m ----
    float v = 0.f;
    float dg = FLT_MAX;
    if (lane < KK) {
        float rm = pd[w][lane][0];
#pragma unroll
        for (int j = 1; j < KK; ++j) rm = fminf(rm, pd[w][lane][j]);
        float cm = pd[w][0][lane];
#pragma unroll
        for (int j = 1; j < KK; ++j) cm = fminf(cm, pd[w][j][lane]);
        v = rm + cm;
        dg = pd[w][lane][KK];   // gt column
    }
#pragma unroll
    for (int off = 16; off > 0; off >>= 1) {
        v += __shfl_xor(v, off, 32);
        dg = fminf(dg, __shfl_xor(dg, off, 32));
    }

    if (lane == 0) {
        const size_t o = ((size_t)b * MM + (m0 + w)) * AA + a;
        ws_cham[o] = v * (1.0f / KK);
        ws_gt[o]   = dg;
    }
}

// Single block: mean over A, min over M, mean over B, write 3 outputs.
__global__ __launch_bounds__(512) void imle_final_kernel(
    const float* __restrict__ ws_cham,
    const float* __restrict__ ws_gt,
    float* __restrict__ out)
{
    __shared__ float ch[BB * MM], gv[BB * MM];
    __shared__ float mch[BB], mgt[BB];
    const int tid = threadIdx.x;  // 512 == B*M
    const int b = tid / MM, m = tid % MM;

    float sc = 0.f, sg = 0.f;
#pragma unroll
    for (int a = 0; a < AA; ++a) {
        sc += ws_cham[((size_t)b * MM + m) * AA + a];
        sg += ws_gt[((size_t)b * MM + m) * AA + a];
    }
    ch[tid] = sc * (1.0f / AA);
    gv[tid] = sg * (1.0f / AA);
    __syncthreads();

    if (tid < BB) {
        float c = ch[tid * MM], g = gv[tid * MM];
        for (int j = 1; j < MM; ++j) {
            c = fminf(c, ch[tid * MM + j]);
            g = fminf(g, gv[tid * MM + j]);
        }
        mch[tid] = c;
        mgt[tid] = g;
    }
    __syncthreads();

    if (tid == 0) {
        float lc = 0.f, lg = 0.f;
        for (int j = 0; j < BB; ++j) { lc += mch[j]; lg += mgt[j]; }
        lc *= (1.0f / BB);
        lg *= (1.0f / BB);
        out[0] = lc + lg;
        out[1] = lc;
        out[2] = lg;
    }
}

extern "C" void kernel_launch(void* const* d_in, const int* in_sizes, int n_in,
                              void* d_out, int out_size, void* d_ws, size_t ws_size,
                              hipStream_t stream) {
    const float* gen = (const float*)d_in[0];
    const float* tgt = (const float*)d_in[1];
    const float* gt  = (const float*)d_in[2];
    float* ws_cham = (float*)d_ws;                 // B*M*A floats
    float* ws_gt   = ws_cham + BB * MM * AA;       // B*M*A floats
    float* out     = (float*)d_out;

    imle_part_kernel<<<BB * AA * (MM / 4), 256, 0, stream>>>(gen, tgt, gt, ws_cham, ws_gt);
    imle_final_kernel<<<1, 512, 0, stream>>>(ws_cham, ws_gt, out);
}

// Round 7
// 81.478 us; speedup vs baseline: 1.0360x; 1.0360x over previous
//
#include <hip/hip_runtime.h>
#include <float.h>

#define BB 16
#define MM 32
#define KK 20
#define AA 8
#define TT 30
#define TD 60          // T*D floats per trajectory
#define NS 15          // float4 steps per trajectory (2 t-steps each)
#define KT 22          // target rows: 20 real + gt (row 20) + dummy (row 21)
#define PDS 21         // pd row stride in floats

// One block = 2 waves = 2 m's sharing the target tile, for a fixed (b, a).
// grid = B*A*(M/2) = 2048 -> exactly 8 blocks/CU (LDS 18.24 KB) -> 16 waves/CU,
// perfectly balanced. Software-pipelined s-loop hides LDS latency in-wave.
// k-map: k = tk + 5i (tk<5); kp = tkp + 11j (tkp<11); 55 lanes cover 20x22
// (col 20 = gt, col 21 = dummy). Unpadded 240B rows: the 4 i-addresses hit
// disjoint bank quads {0,12,24,4}+..., tkp aliases are <=2-way (free).
__global__ __launch_bounds__(128, 4) void imle_part_kernel(
    const float* __restrict__ gen,   // B M K A T D
    const float* __restrict__ tgt,   // B K A T D
    const float* __restrict__ gt,    // B A T D
    float* __restrict__ ws_cham,     // [B][M][A]
    float* __restrict__ ws_gt)       // [B][M][A]
{
    __shared__ float4 sg[2][KK][NS];   // 2 m-slices of gen, x50
    __shared__ float4 st[KT][NS];      // target rows (x50) + gt row (metric) + dummy
    __shared__ float  pd[2][KK][PDS];  // per-m pairwise mean distances

    const int blk = blockIdx.x;        // grid = 2048
    const int mg = blk & 15;           // m-group (M/2 = 16)
    const int a  = (blk >> 4) & 7;
    const int b  = blk >> 7;
    const int m0 = mg * 2;
    const int tid = threadIdx.x;

    // ---- stage gen: 2m x 20k rows of 15 float4 ----
    for (int idx = tid; idx < 40 * NS; idx += 128) {
        int row = idx / NS, q = idx - row * NS;
        int mi = row / KK, k = row - mi * KK;
        float4 v = ((const float4*)(gen +
            (size_t)(((b * MM + m0 + mi) * KK + k) * AA + a) * TD))[q];
        v.x *= 50.f; v.y *= 50.f; v.z *= 50.f; v.w *= 50.f;
        sg[mi][k][q] = v;
    }
    // ---- stage target rows 0..19 (x50), row 20 = gt (metric), row 21 = zeros ----
    for (int idx = tid; idx < KT * NS; idx += 128) {
        int row = idx / NS, q = idx - row * NS;
        float4 v;
        if (row < KK) {
            v = ((const float4*)(tgt + (size_t)((b * KK + row) * AA + a) * TD))[q];
            v.x *= 50.f; v.y *= 50.f; v.z *= 50.f; v.w *= 50.f;
        } else if (row == KK) {
            v = ((const float4*)(gt + (size_t)(b * AA + a) * TD))[q];
        } else {
            v = make_float4(0.f, 0.f, 0.f, 0.f);
        }
        st[row][q] = v;
    }
    __syncthreads();

    const int w = tid >> 6;        // wave id -> m offset (0 or 1)
    const int lane = tid & 63;

    // ---- pairwise distances: 4x2 register tile, software-pipelined s-loop ----
    if (lane < 55) {
        const int tk  = lane / 11;       // k  = tk + 5i
        const int tkp = lane - tk * 11;  // kp = tkp + 11j
        float acc[4][2] = {{0.f, 0.f}, {0.f, 0.f}, {0.f, 0.f}, {0.f, 0.f}};

        float4 gv[4], tv[2];
#pragma unroll
        for (int i = 0; i < 4; ++i) gv[i] = sg[w][tk + 5 * i][0];
        tv[0] = st[tkp][0];
        tv[1] = st[tkp + 11][0];

#pragma unroll 2
        for (int s = 0; s < NS - 1; ++s) {
            // prefetch s+1 (independent of current compute)
            float4 ngv[4], ntv[2];
#pragma unroll
            for (int i = 0; i < 4; ++i) ngv[i] = sg[w][tk + 5 * i][s + 1];
            ntv[0] = st[tkp][s + 1];
            ntv[1] = st[tkp + 11][s + 1];
            // compute on current
#pragma unroll
            for (int i = 0; i < 4; ++i) {
#pragma unroll
                for (int j = 0; j < 2; ++j) {
                    float dx1 = gv[i].x - tv[j].x;
                    float dy1 = gv[i].y - tv[j].y;
                    float dx2 = gv[i].z - tv[j].z;
                    float dy2 = gv[i].w - tv[j].w;
                    acc[i][j] += __builtin_amdgcn_sqrtf(fmaf(dy1, dy1, dx1 * dx1))
                               + __builtin_amdgcn_sqrtf(fmaf(dy2, dy2, dx2 * dx2));
                }
            }
#pragma unroll
            for (int i = 0; i < 4; ++i) gv[i] = ngv[i];
            tv[0] = ntv[0];
            tv[1] = ntv[1];
        }
        // epilogue: s = NS-1
#pragma unroll
        for (int i = 0; i < 4; ++i) {
#pragma unroll
            for (int j = 0; j < 2; ++j) {
                float dx1 = gv[i].x - tv[j].x;
                float dy1 = gv[i].y - tv[j].y;
                float dx2 = gv[i].z - tv[j].z;
                float dy2 = gv[i].w - tv[j].w;
                acc[i][j] += __builtin_amdgcn_sqrtf(fmaf(dy1, dy1, dx1 * dx1))
                           + __builtin_amdgcn_sqrtf(fmaf(dy2, dy2, dx2 * dx2));
            }
        }

        const float inv_t = 1.0f / TT;
#pragma unroll
        for (int i = 0; i < 4; ++i) {
            pd[w][tk + 5 * i][tkp] = acc[i][0] * inv_t;   // kp = tkp <= 10, always real
            if (tkp + 11 <= KK)                           // col 21 is dummy
                pd[w][tk + 5 * i][tkp + 11] = acc[i][1] * inv_t;
        }
    }
    __syncthreads();

    // ---- row/col mins over 20x20 + gt col, per wave / per m ----
    float v = 0.f;
    float dg = FLT_MAX;
    if (lane < KK) {
        float rm = pd[w][lane][0];
#pragma unroll
        for (int j = 1; j < KK; ++j) rm = fminf(rm, pd[w][lane][j]);
        float cm = pd[w][0][lane];
#pragma unroll
        for (int j = 1; j < KK; ++j) cm = fminf(cm, pd[w][j][lane]);
        v = rm + cm;
        dg = pd[w][lane][KK];   // gt column
    }
#pragma unroll
    for (int off = 16; off > 0; off >>= 1) {
        v += __shfl_xor(v, off, 32);
        dg = fminf(dg, __shfl_xor(dg, off, 32));
    }

    if (lane == 0) {
        const size_t o = ((size_t)b * MM + (m0 + w)) * AA + a;
        ws_cham[o] = v * (1.0f / KK);
        ws_gt[o]   = dg;
    }
}

// Single block: mean over A, min over M, mean over B, write 3 outputs.
__global__ __launch_bounds__(512) void imle_final_kernel(
    const float* __restrict__ ws_cham,
    const float* __restrict__ ws_gt,
    float* __restrict__ out)
{
    __shared__ float ch[BB * MM], gv[BB * MM];
    __shared__ float mch[BB], mgt[BB];
    const int tid = threadIdx.x;  // 512 == B*M
    const int b = tid / MM, m = tid % MM;

    float sc = 0.f, sg = 0.f;
#pragma unroll
    for (int a = 0; a < AA; ++a) {
        sc += ws_cham[((size_t)b * MM + m) * AA + a];
        sg += ws_gt[((size_t)b * MM + m) * AA + a];
    }
    ch[tid] = sc * (1.0f / AA);
    gv[tid] = sg * (1.0f / AA);
    __syncthreads();

    if (tid < BB) {
        float c = ch[tid * MM], g = gv[tid * MM];
        for (int j = 1; j < MM; ++j) {
            c = fminf(c, ch[tid * MM + j]);
            g = fminf(g, gv[tid * MM + j]);
        }
        mch[tid] = c;
        mgt[tid] = g;
    }
    __syncthreads();

    if (tid == 0) {
        float lc = 0.f, lg = 0.f;
        for (int j = 0; j < BB; ++j) { lc += mch[j]; lg += mgt[j]; }
        lc *= (1.0f / BB);
        lg *= (1.0f / BB);
        out[0] = lc + lg;
        out[1] = lc;
        out[2] = lg;
    }
}

extern "C" void kernel_launch(void* const* d_in, const int* in_sizes, int n_in,
                              void* d_out, int out_size, void* d_ws, size_t ws_size,
                              hipStream_t stream) {
    const float* gen = (const float*)d_in[0];
    const float* tgt = (const float*)d_in[1];
    const float* gt  = (const float*)d_in[2];
    float* ws_cham = (float*)d_ws;                 // B*M*A floats
    float* ws_gt   = ws_cham + BB * MM * AA;       // B*M*A floats
    float* out     = (float*)d_out;

    imle_part_kernel<<<BB * AA * (MM / 2), 128, 0, stream>>>(gen, tgt, gt, ws_cham, ws_gt);
    imle_final_kernel<<<1, 512, 0, stream>>>(ws_cham, ws_gt, out);
}